// Round 4
// baseline (690.519 us; speedup 1.0000x reference)
//
#include <hip/hip_runtime.h>

#define CHUNK 8192           // edges per block in coarse pass
#define BMAX 512             // max coarse buckets (N/256 <= 512)
#define GROWS 128            // rows per gemm1 block

// ---------------- coarse bucket histogram ----------------

__global__ __launch_bounds__(256) void k_coarse_hist(const int* __restrict__ dst, int E,
                                                     int* __restrict__ bc,
                                                     int* __restrict__ blockBase, int B) {
    __shared__ int cnt[BMAX];
    int t = threadIdx.x;
    cnt[t] = 0; cnt[t + 256] = 0;
    __syncthreads();
    int e0 = blockIdx.x * CHUNK;
#pragma unroll
    for (int it = 0; it < CHUNK / 256; ++it) {
        int e = e0 + it * 256 + t;
        if (e < E) atomicAdd(&cnt[dst[e] >> 8], 1);
    }
    __syncthreads();
    for (int b = t; b < B; b += 256) {
        int c = cnt[b];
        if (c > 0) blockBase[(size_t)blockIdx.x * B + b] = atomicAdd(&bc[b], c);
    }
}

// single block, 512 threads; exclusive scan in place (n <= 512)
__global__ void k_scan_bsums(int* bsums, int nb) {
    __shared__ int s[2][512];
    int t = threadIdx.x;
    int v = (t < nb) ? bsums[t] : 0;
    int p = 0;
    s[0][t] = v;
    __syncthreads();
    for (int off = 1; off < 512; off <<= 1) {
        s[p ^ 1][t] = s[p][t] + ((t >= off) ? s[p][t - off] : 0);
        p ^= 1;
        __syncthreads();
    }
    if (t < nb) bsums[t] = s[p][t] - v;  // exclusive
}

// ---------------- coarse scatter ----------------

__global__ __launch_bounds__(256) void k_coarse_scatter(const int* __restrict__ src,
                                                        const int* __restrict__ dst, int E,
                                                        const int* __restrict__ bucketBase,
                                                        const int* __restrict__ blockBase, int B,
                                                        unsigned int* __restrict__ ebuf) {
    __shared__ int run[BMAX];
    int t = threadIdx.x;
    run[t] = 0; run[t + 256] = 0;
    __syncthreads();
    int e0 = blockIdx.x * CHUNK;
#pragma unroll
    for (int it = 0; it < CHUNK / 256; ++it) {
        int e = e0 + it * 256 + t;
        if (e < E) {
            int d = dst[e];
            int b = d >> 8;
            int rank = atomicAdd(&run[b], 1);
            int pos = bucketBase[b] + blockBase[(size_t)blockIdx.x * B + b] + rank;
            ebuf[pos] = ((unsigned int)(d & 255) << 24) | (unsigned int)src[e];
        }
    }
}

// ---------------- per-node degree histogram + dinv from bucketed edges ----------------

__global__ __launch_bounds__(256) void k_bucket_hist(const unsigned int* __restrict__ ebuf,
                                                     const int* __restrict__ bucketBase,
                                                     int E, int N, int B,
                                                     int* __restrict__ hist,
                                                     float* __restrict__ dinv) {
    __shared__ int cnt[256];
    int t = threadIdx.x;
    int b = blockIdx.x;
    cnt[t] = 0;
    __syncthreads();
    int e0 = bucketBase[b];
    int e1 = (b + 1 < B) ? bucketBase[b + 1] : E;
    for (int e = e0 + t; e < e1; e += 256) atomicAdd(&cnt[ebuf[e] >> 24], 1);
    __syncthreads();
    int node = b * 256 + t;
    if (node < N) {
        hist[node] = cnt[t];
        dinv[node] = rsqrtf((float)(cnt[t] + 1));  // +1 self-loop
    }
}

// ---------------- fine scatter (fused rowStart scan): bucket -> CSR ----------------
// bucketBase[b] IS the CSR base of node b*256, so rowStart = bucketBase[b] +
// within-block exclusive scan of hist.

__global__ __launch_bounds__(256) void k_fine_scatter(const unsigned int* __restrict__ ebuf,
                                                      const int* __restrict__ bucketBase,
                                                      const int* __restrict__ hist,
                                                      int E, int N, int B,
                                                      int* __restrict__ rowStart,
                                                      int* __restrict__ csr_src) {
    __shared__ int s[2][256];
    __shared__ int cnt[256];
    int t = threadIdx.x;
    int b = blockIdx.x;
    int node = b * 256 + t;
    int v = (node < N) ? hist[node] : 0;
    int p = 0;
    s[0][t] = v;
    __syncthreads();
    for (int off = 1; off < 256; off <<= 1) {
        s[p ^ 1][t] = s[p][t] + ((t >= off) ? s[p][t - off] : 0);
        p ^= 1;
        __syncthreads();
    }
    int rs = bucketBase[b] + s[p][t] - v;
    if (node < N) rowStart[node] = rs;
    cnt[t] = rs;
    __syncthreads();
    int e0 = bucketBase[b];
    int e1 = (b + 1 < B) ? bucketBase[b + 1] : E;
    for (int e = e0 + t; e < e1; e += 256) {
        unsigned int w = ebuf[e];
        int pos = atomicAdd(&cnt[w >> 24], 1);
        csr_src[pos] = (int)(w & 0xFFFFFFu);
    }
}

// ---------------- GEMM1: h1 = (X @ W1) * dinv[row]  ----------------
// 128 rows/block, double-buffered LDS, prefetch chunk ch+1 into VGPRs while
// computing chunk ch. One barrier per chunk; load latency hidden behind FMAs.

__global__ __launch_bounds__(128) void k_gemm1(const float* __restrict__ x,
                                               const float* __restrict__ W1,
                                               const float* __restrict__ dinv,
                                               int N, float* __restrict__ h1) {
    __shared__ float xs[2][GROWS * 36];  // 2 x 18 KB; stride 36 -> 0 bank conflicts (measured)
    const int t = threadIdx.x;
    const int R0 = blockIdx.x * GROWS;

    float acc[16];
#pragma unroll
    for (int c = 0; c < 16; ++c) acc[c] = 0.0f;

    float4 pre[8];
    // prologue: load + stage chunk 0
#pragma unroll
    for (int it = 0; it < 8; ++it) {
        int f = t + GROWS * it;
        int r = f >> 3, j4 = f & 7;
        int row = R0 + r;
        pre[it] = make_float4(0.f, 0.f, 0.f, 0.f);
        if (row < N) pre[it] = *(const float4*)(x + (size_t)row * 512 + j4 * 4);
    }
#pragma unroll
    for (int it = 0; it < 8; ++it) {
        int f = t + GROWS * it;
        int r = f >> 3, j4 = f & 7;
        *(float4*)(&xs[0][r * 36 + j4 * 4]) = pre[it];
    }
    __syncthreads();

    int p = 0;
    for (int ch = 0; ch < 16; ++ch) {
        // prefetch chunk ch+1 (loads in flight during compute below)
        if (ch + 1 < 16) {
#pragma unroll
            for (int it = 0; it < 8; ++it) {
                int f = t + GROWS * it;
                int r = f >> 3, j4 = f & 7;
                int row = R0 + r;
                pre[it] = make_float4(0.f, 0.f, 0.f, 0.f);
                if (row < N) pre[it] = *(const float4*)(x + (size_t)row * 512 + (ch + 1) * 32 + j4 * 4);
            }
        }
        // compute chunk ch from LDS
        const float4* xr = (const float4*)(&xs[p][t * 36]);
#pragma unroll
        for (int j4 = 0; j4 < 8; ++j4) {
            float4 xv = xr[j4];
            float xe[4] = {xv.x, xv.y, xv.z, xv.w};
            int k = ch * 32 + j4 * 4;
#pragma unroll
            for (int d = 0; d < 4; ++d) {
                const float* w = W1 + (k + d) * 16;  // wave-uniform -> scalar loads
#pragma unroll
                for (int c = 0; c < 16; ++c) acc[c] = fmaf(xe[d], w[c], acc[c]);
            }
        }
        // stage chunk ch+1 into the other buffer
        if (ch + 1 < 16) {
#pragma unroll
            for (int it = 0; it < 8; ++it) {
                int f = t + GROWS * it;
                int r = f >> 3, j4 = f & 7;
                *(float4*)(&xs[p ^ 1][r * 36 + j4 * 4]) = pre[it];
            }
            __syncthreads();
        }
        p ^= 1;
    }

    int row = R0 + t;
    if (row < N) {
        float di = dinv[row];
#pragma unroll
        for (int c = 0; c < 16; ++c) acc[c] *= di;
        float4* o = (float4*)(h1 + (size_t)row * 16);
        o[0] = make_float4(acc[0], acc[1], acc[2], acc[3]);
        o[1] = make_float4(acc[4], acc[5], acc[6], acc[7]);
        o[2] = make_float4(acc[8], acc[9], acc[10], acc[11]);
        o[3] = make_float4(acc[12], acc[13], acc[14], acc[15]);
    }
}

// ---------------- Aggregation layer 1: relu1 = relu(di * sum(h1') + b1) ----------------
// h1 is pre-scaled by dinv[src]; di factored out of the sum.

__global__ void k_gather1(const float* __restrict__ h1, const int* __restrict__ csr_src,
                          const int* __restrict__ rowStart, const int* __restrict__ hist,
                          const float* __restrict__ dinv, const float* __restrict__ b1,
                          int N, float* __restrict__ relu1) {
    int g = blockIdx.x * blockDim.x + threadIdx.x;
    int i = g >> 4, c = g & 15;
    if (i >= N) return;
    float ssum = h1[(size_t)i * 16 + c];  // self-loop (already * dinv[i])
    int e0 = rowStart[i], e1 = e0 + hist[i];
    for (int e = e0; e < e1; ++e) {
        int s = csr_src[e];
        ssum += h1[(size_t)s * 16 + c];
    }
    float v = fmaf(dinv[i], ssum, b1[c]);
    relu1[(size_t)i * 16 + c] = fmaxf(v, 0.0f);
}

// ---------------- h2 = (relu1 @ W2) * dinv[i]  (W2 [16,7]) ----------------

__global__ void k_h2(const float* __restrict__ relu1, const float* __restrict__ W2,
                     const float* __restrict__ dinv, int N, float* __restrict__ h2) {
    int i = blockIdx.x * blockDim.x + threadIdx.x;
    if (i >= N) return;
    float r[16];
#pragma unroll
    for (int q = 0; q < 4; ++q) {
        float4 v = *(const float4*)(relu1 + (size_t)i * 16 + q * 4);
        r[q * 4 + 0] = v.x; r[q * 4 + 1] = v.y; r[q * 4 + 2] = v.z; r[q * 4 + 3] = v.w;
    }
    float di = dinv[i];
#pragma unroll
    for (int c2 = 0; c2 < 7; ++c2) {
        float a = 0.0f;
#pragma unroll
        for (int c = 0; c < 16; ++c) a = fmaf(r[c], W2[c * 7 + c2], a);
        h2[(size_t)i * 7 + c2] = a * di;
    }
}

// ---------------- Aggregation layer 2: out = di * sum(h2') + b2 ----------------

__global__ void k_gather2(const float* __restrict__ h2, const int* __restrict__ csr_src,
                          const int* __restrict__ rowStart, const int* __restrict__ hist,
                          const float* __restrict__ dinv, const float* __restrict__ b2,
                          int N, float* __restrict__ out) {
    int g = blockIdx.x * blockDim.x + threadIdx.x;
    int i = g >> 3, c = g & 7;
    if (i >= N || c >= 7) return;
    float ssum = h2[(size_t)i * 7 + c];
    int e0 = rowStart[i], e1 = e0 + hist[i];
    for (int e = e0; e < e1; ++e) {
        int s = csr_src[e];
        ssum += h2[(size_t)s * 7 + c];
    }
    out[(size_t)i * 7 + c] = fmaf(dinv[i], ssum, b2[c]);
}

// ---------------- launch ----------------

extern "C" void kernel_launch(void* const* d_in, const int* in_sizes, int n_in,
                              void* d_out, int out_size, void* d_ws, size_t ws_size,
                              hipStream_t stream) {
    const float* x  = (const float*)d_in[0];
    const int*   ei = (const int*)d_in[1];
    const float* W1 = (const float*)d_in[2];
    const float* b1 = (const float*)d_in[3];
    const float* W2 = (const float*)d_in[4];
    const float* b2 = (const float*)d_in[5];
    float* out = (float*)d_out;

    const int N = in_sizes[0] / 512;
    const int E = in_sizes[1] / 2;
    const int* src = ei;       // edge_index[0]
    const int* dst = ei + E;   // edge_index[1]

    const int nb  = (N + 255) / 256;           // 391 node blocks == coarse buckets
    const int B   = nb;
    const int nbA = (E + CHUNK - 1) / CHUNK;   // 391 coarse blocks
    const int nbG = (N + GROWS - 1) / GROWS;   // 782 gemm1 blocks

    char* ws = (char*)d_ws;
    auto alloc = [&](size_t bytes) {
        char* p = ws;
        ws += (bytes + 511) & ~(size_t)511;
        return p;
    };
    // persistent region
    int*   hist      = (int*)alloc((size_t)N * 4);
    float* dinv      = (float*)alloc((size_t)N * 4);
    int*   rowStart  = (int*)alloc((size_t)N * 4);
    int*   bc        = (int*)alloc((size_t)(B + 1) * 4);
    int*   blockBase = (int*)alloc((size_t)nbA * B * 4);
    int*   csr_src   = (int*)alloc((size_t)E * 4);
    // overlapped region: ebuf (dead after fine_scatter) unions with h1/relu1/h2
    size_t featBytes = (size_t)N * 16 * 4 * 2 + (size_t)N * 7 * 4;
    size_t ebufBytes = (size_t)E * 4;
    char* regB = alloc(featBytes > ebufBytes ? featBytes : ebufBytes);
    unsigned int* ebuf = (unsigned int*)regB;
    float* h1    = (float*)regB;
    float* relu1 = h1 + (size_t)N * 16;
    float* h2    = relu1 + (size_t)N * 16;

    hipMemsetAsync(bc, 0, (size_t)B * 4, stream);
    k_coarse_hist<<<nbA, 256, 0, stream>>>(dst, E, bc, blockBase, B);
    k_scan_bsums<<<1, 512, 0, stream>>>(bc, B);                       // bc -> bucketBase
    k_coarse_scatter<<<nbA, 256, 0, stream>>>(src, dst, E, bc, blockBase, B, ebuf);
    k_bucket_hist<<<B, 256, 0, stream>>>(ebuf, bc, E, N, B, hist, dinv);
    k_fine_scatter<<<B, 256, 0, stream>>>(ebuf, bc, hist, E, N, B, rowStart, csr_src);
    k_gemm1<<<nbG, GROWS, 0, stream>>>(x, W1, dinv, N, h1);
    k_gather1<<<(N * 16 + 255) / 256, 256, 0, stream>>>(h1, csr_src, rowStart, hist, dinv, b1, N, relu1);
    k_h2<<<nb, 256, 0, stream>>>(relu1, W2, dinv, N, h2);
    k_gather2<<<(N * 8 + 255) / 256, 256, 0, stream>>>(h2, csr_src, rowStart, hist, dinv, b2, N, out);
}

// Round 5
// 579.129 us; speedup vs baseline: 1.1923x; 1.1923x over previous
//
#include <hip/hip_runtime.h>

#define CHUNK 8192           // edges per block in coarse pass
#define BMAX 512             // max coarse buckets (N/256 <= 512)

typedef __attribute__((address_space(3))) unsigned int lds_u32;
typedef const __attribute__((address_space(1))) unsigned int glb_u32;

// async 16B global -> LDS (global_load_lds_dwordx4). HW dest = wave-uniform
// base + lane*16, which our flat slot layout satisfies exactly.
__device__ __forceinline__ void gload16(const float* g, float* l) {
    __builtin_amdgcn_global_load_lds((glb_u32*)g, (lds_u32*)l, 16, 0, 0);
}

// ---------------- coarse bucket histogram ----------------

__global__ __launch_bounds__(256) void k_coarse_hist(const int* __restrict__ dst, int E,
                                                     int* __restrict__ bc,
                                                     int* __restrict__ blockBase, int B) {
    __shared__ int cnt[BMAX];
    int t = threadIdx.x;
    cnt[t] = 0; cnt[t + 256] = 0;
    __syncthreads();
    int e0 = blockIdx.x * CHUNK;
#pragma unroll
    for (int it = 0; it < CHUNK / 256; ++it) {
        int e = e0 + it * 256 + t;
        if (e < E) atomicAdd(&cnt[dst[e] >> 8], 1);
    }
    __syncthreads();
    for (int b = t; b < B; b += 256) {
        int c = cnt[b];
        if (c > 0) blockBase[(size_t)blockIdx.x * B + b] = atomicAdd(&bc[b], c);
    }
}

// single block, 512 threads; exclusive scan in place (n <= 512)
__global__ void k_scan_bsums(int* bsums, int nb) {
    __shared__ int s[2][512];
    int t = threadIdx.x;
    int v = (t < nb) ? bsums[t] : 0;
    int p = 0;
    s[0][t] = v;
    __syncthreads();
    for (int off = 1; off < 512; off <<= 1) {
        s[p ^ 1][t] = s[p][t] + ((t >= off) ? s[p][t - off] : 0);
        p ^= 1;
        __syncthreads();
    }
    if (t < nb) bsums[t] = s[p][t] - v;  // exclusive
}

// ---------------- coarse scatter ----------------

__global__ __launch_bounds__(256) void k_coarse_scatter(const int* __restrict__ src,
                                                        const int* __restrict__ dst, int E,
                                                        const int* __restrict__ bucketBase,
                                                        const int* __restrict__ blockBase, int B,
                                                        unsigned int* __restrict__ ebuf) {
    __shared__ int run[BMAX];
    int t = threadIdx.x;
    run[t] = 0; run[t + 256] = 0;
    __syncthreads();
    int e0 = blockIdx.x * CHUNK;
#pragma unroll
    for (int it = 0; it < CHUNK / 256; ++it) {
        int e = e0 + it * 256 + t;
        if (e < E) {
            int d = dst[e];
            int b = d >> 8;
            int rank = atomicAdd(&run[b], 1);
            int pos = bucketBase[b] + blockBase[(size_t)blockIdx.x * B + b] + rank;
            ebuf[pos] = ((unsigned int)(d & 255) << 24) | (unsigned int)src[e];
        }
    }
}

// ---------------- per-node degree histogram + dinv from bucketed edges ----------------

__global__ __launch_bounds__(256) void k_bucket_hist(const unsigned int* __restrict__ ebuf,
                                                     const int* __restrict__ bucketBase,
                                                     int E, int N, int B,
                                                     int* __restrict__ hist,
                                                     float* __restrict__ dinv) {
    __shared__ int cnt[256];
    int t = threadIdx.x;
    int b = blockIdx.x;
    cnt[t] = 0;
    __syncthreads();
    int e0 = bucketBase[b];
    int e1 = (b + 1 < B) ? bucketBase[b + 1] : E;
    for (int e = e0 + t; e < e1; e += 256) atomicAdd(&cnt[ebuf[e] >> 24], 1);
    __syncthreads();
    int node = b * 256 + t;
    if (node < N) {
        hist[node] = cnt[t];
        dinv[node] = rsqrtf((float)(cnt[t] + 1));  // +1 self-loop
    }
}

// ---------------- fine scatter (fused rowStart scan): bucket -> CSR ----------------

__global__ __launch_bounds__(256) void k_fine_scatter(const unsigned int* __restrict__ ebuf,
                                                      const int* __restrict__ bucketBase,
                                                      const int* __restrict__ hist,
                                                      int E, int N, int B,
                                                      int* __restrict__ rowStart,
                                                      int* __restrict__ csr_src) {
    __shared__ int s[2][256];
    __shared__ int cnt[256];
    int t = threadIdx.x;
    int b = blockIdx.x;
    int node = b * 256 + t;
    int v = (node < N) ? hist[node] : 0;
    int p = 0;
    s[0][t] = v;
    __syncthreads();
    for (int off = 1; off < 256; off <<= 1) {
        s[p ^ 1][t] = s[p][t] + ((t >= off) ? s[p][t - off] : 0);
        p ^= 1;
        __syncthreads();
    }
    int rs = bucketBase[b] + s[p][t] - v;
    if (node < N) rowStart[node] = rs;
    cnt[t] = rs;
    __syncthreads();
    int e0 = bucketBase[b];
    int e1 = (b + 1 < B) ? bucketBase[b + 1] : E;
    for (int e = e0 + t; e < e1; e += 256) {
        unsigned int w = ebuf[e];
        int pos = atomicAdd(&cnt[w >> 24], 1);
        csr_src[pos] = (int)(w & 0xFFFFFFu);
    }
}

// ---------------- GEMM1: h1 = (X @ W1) * dinv[row] ----------------
// 256 rows/block. Double-buffered 2x32KB LDS, async global_load_lds (16B)
// direct-to-LDS: issue chunk ch+1 -> buf p^1, compute ch from buf p, one
// barrier/chunk. XOR swizzle (slot s holds row s>>3, k-group (s&7)^(row&7))
// makes the flat DMA layout conflict-free for the stride-128B ds_read_b128.

__global__ __launch_bounds__(256) void k_gemm1(const float* __restrict__ x,
                                               const float* __restrict__ W1,
                                               const float* __restrict__ dinv,
                                               int N, float* __restrict__ h1) {
    __shared__ float xs[2][256 * 32];  // 2 x 32 KB
    const int t = threadIdx.x;
    const int R0 = blockIdx.x * 256;
    const int tk = t & 7;

    // per-lane global base (chunk 0) and LDS slot for each of 8 issues
    const float* gbase[8];
#pragma unroll
    for (int it = 0; it < 8; ++it) {
        int r = it * 32 + (t >> 3);        // row handled by this lane-slot
        int j4 = tk ^ (r & 7);             // swizzled k-group stored here
        int row = R0 + r;
        if (row >= N) row = N - 1;         // clamp: garbage lands in never-stored accs
        gbase[it] = x + (size_t)row * 512 + j4 * 4;
    }

    float acc[16];
#pragma unroll
    for (int c = 0; c < 16; ++c) acc[c] = 0.0f;

    // prologue: chunk 0 -> buf 0
#pragma unroll
    for (int it = 0; it < 8; ++it)
        gload16(gbase[it], &xs[0][(it * 256 + t) * 4]);
    __syncthreads();  // vmcnt(0) drain + barrier

    int p = 0;
    for (int ch = 0; ch < 16; ++ch) {
        if (ch + 1 < 16) {
#pragma unroll
            for (int it = 0; it < 8; ++it)
                gload16(gbase[it] + (ch + 1) * 32, &xs[p ^ 1][(it * 256 + t) * 4]);
        }
        // compute chunk ch from buf p; j4 = physical k-group (W1 idx wave-uniform)
        const float* xr = &xs[p][t * 32];
#pragma unroll
        for (int j4 = 0; j4 < 8; ++j4) {
            float4 xv = *(const float4*)(xr + ((j4 ^ tk) << 2));
            float xe[4] = {xv.x, xv.y, xv.z, xv.w};
            int k = ch * 32 + j4 * 4;
#pragma unroll
            for (int d = 0; d < 4; ++d) {
                const float* w = W1 + (k + d) * 16;  // wave-uniform -> s_load
#pragma unroll
                for (int c = 0; c < 16; ++c) acc[c] = fmaf(xe[d], w[c], acc[c]);
            }
        }
        __syncthreads();  // prefetch had ~1024 cyc of FMA cover before this drain
        p ^= 1;
    }

    int row = R0 + t;
    if (row < N) {
        float di = dinv[row];
#pragma unroll
        for (int c = 0; c < 16; ++c) acc[c] *= di;
        float4* o = (float4*)(h1 + (size_t)row * 16);
        o[0] = make_float4(acc[0], acc[1], acc[2], acc[3]);
        o[1] = make_float4(acc[4], acc[5], acc[6], acc[7]);
        o[2] = make_float4(acc[8], acc[9], acc[10], acc[11]);
        o[3] = make_float4(acc[12], acc[13], acc[14], acc[15]);
    }
}

// ---------------- Aggregation layer 1: relu1 = relu(di * sum(h1') + b1) ----------------

__global__ void k_gather1(const float* __restrict__ h1, const int* __restrict__ csr_src,
                          const int* __restrict__ rowStart, const int* __restrict__ hist,
                          const float* __restrict__ dinv, const float* __restrict__ b1,
                          int N, float* __restrict__ relu1) {
    int g = blockIdx.x * blockDim.x + threadIdx.x;
    int i = g >> 4, c = g & 15;
    if (i >= N) return;
    float ssum = h1[(size_t)i * 16 + c];  // self-loop (already * dinv[i])
    int e0 = rowStart[i], e1 = e0 + hist[i];
    for (int e = e0; e < e1; ++e) {
        int s = csr_src[e];
        ssum += h1[(size_t)s * 16 + c];
    }
    float v = fmaf(dinv[i], ssum, b1[c]);
    relu1[(size_t)i * 16 + c] = fmaxf(v, 0.0f);
}

// ---------------- h2 = (relu1 @ W2) * dinv[i]  (W2 [16,7]) ----------------

__global__ void k_h2(const float* __restrict__ relu1, const float* __restrict__ W2,
                     const float* __restrict__ dinv, int N, float* __restrict__ h2) {
    int i = blockIdx.x * blockDim.x + threadIdx.x;
    if (i >= N) return;
    float r[16];
#pragma unroll
    for (int q = 0; q < 4; ++q) {
        float4 v = *(const float4*)(relu1 + (size_t)i * 16 + q * 4);
        r[q * 4 + 0] = v.x; r[q * 4 + 1] = v.y; r[q * 4 + 2] = v.z; r[q * 4 + 3] = v.w;
    }
    float di = dinv[i];
#pragma unroll
    for (int c2 = 0; c2 < 7; ++c2) {
        float a = 0.0f;
#pragma unroll
        for (int c = 0; c < 16; ++c) a = fmaf(r[c], W2[c * 7 + c2], a);
        h2[(size_t)i * 7 + c2] = a * di;
    }
}

// ---------------- Aggregation layer 2: out = di * sum(h2') + b2 ----------------

__global__ void k_gather2(const float* __restrict__ h2, const int* __restrict__ csr_src,
                          const int* __restrict__ rowStart, const int* __restrict__ hist,
                          const float* __restrict__ dinv, const float* __restrict__ b2,
                          int N, float* __restrict__ out) {
    int g = blockIdx.x * blockDim.x + threadIdx.x;
    int i = g >> 3, c = g & 7;
    if (i >= N || c >= 7) return;
    float ssum = h2[(size_t)i * 7 + c];
    int e0 = rowStart[i], e1 = e0 + hist[i];
    for (int e = e0; e < e1; ++e) {
        int s = csr_src[e];
        ssum += h2[(size_t)s * 7 + c];
    }
    out[(size_t)i * 7 + c] = fmaf(dinv[i], ssum, b2[c]);
}

// ---------------- launch ----------------

extern "C" void kernel_launch(void* const* d_in, const int* in_sizes, int n_in,
                              void* d_out, int out_size, void* d_ws, size_t ws_size,
                              hipStream_t stream) {
    const float* x  = (const float*)d_in[0];
    const int*   ei = (const int*)d_in[1];
    const float* W1 = (const float*)d_in[2];
    const float* b1 = (const float*)d_in[3];
    const float* W2 = (const float*)d_in[4];
    const float* b2 = (const float*)d_in[5];
    float* out = (float*)d_out;

    const int N = in_sizes[0] / 512;
    const int E = in_sizes[1] / 2;
    const int* src = ei;       // edge_index[0]
    const int* dst = ei + E;   // edge_index[1]

    const int nb  = (N + 255) / 256;           // 391 node blocks == coarse buckets
    const int B   = nb;
    const int nbA = (E + CHUNK - 1) / CHUNK;   // 391 coarse blocks

    char* ws = (char*)d_ws;
    auto alloc = [&](size_t bytes) {
        char* p = ws;
        ws += (bytes + 511) & ~(size_t)511;
        return p;
    };
    // persistent region
    int*   hist      = (int*)alloc((size_t)N * 4);
    float* dinv      = (float*)alloc((size_t)N * 4);
    int*   rowStart  = (int*)alloc((size_t)N * 4);
    int*   bc        = (int*)alloc((size_t)(B + 1) * 4);
    int*   blockBase = (int*)alloc((size_t)nbA * B * 4);
    int*   csr_src   = (int*)alloc((size_t)E * 4);
    // overlapped region: ebuf (dead after fine_scatter) unions with h1/relu1/h2
    size_t featBytes = (size_t)N * 16 * 4 * 2 + (size_t)N * 7 * 4;
    size_t ebufBytes = (size_t)E * 4;
    char* regB = alloc(featBytes > ebufBytes ? featBytes : ebufBytes);
    unsigned int* ebuf = (unsigned int*)regB;
    float* h1    = (float*)regB;
    float* relu1 = h1 + (size_t)N * 16;
    float* h2    = relu1 + (size_t)N * 16;

    hipMemsetAsync(bc, 0, (size_t)B * 4, stream);
    k_coarse_hist<<<nbA, 256, 0, stream>>>(dst, E, bc, blockBase, B);
    k_scan_bsums<<<1, 512, 0, stream>>>(bc, B);                       // bc -> bucketBase
    k_coarse_scatter<<<nbA, 256, 0, stream>>>(src, dst, E, bc, blockBase, B, ebuf);
    k_bucket_hist<<<B, 256, 0, stream>>>(ebuf, bc, E, N, B, hist, dinv);
    k_fine_scatter<<<B, 256, 0, stream>>>(ebuf, bc, hist, E, N, B, rowStart, csr_src);
    k_gemm1<<<nb, 256, 0, stream>>>(x, W1, dinv, N, h1);
    k_gather1<<<(N * 16 + 255) / 256, 256, 0, stream>>>(h1, csr_src, rowStart, hist, dinv, b1, N, relu1);
    k_h2<<<nb, 256, 0, stream>>>(relu1, W2, dinv, N, h2);
    k_gather2<<<(N * 8 + 255) / 256, 256, 0, stream>>>(h2, csr_src, rowStart, hist, dinv, b2, N, out);
}